// Round 1
// baseline (120.059 us; speedup 1.0000x reference)
//
#include <hip/hip_runtime.h>
#include <hip/hip_bf16.h>
#include <math.h>

#define BN 32
#define NN 2048
#define KK 32
#define DD 16

// ws layout (floats):
// 0      : accN   [BN*KK]      = 1024
// 1024   : accSx  [BN*KK*DD]   = 16384
// 17408  : accSxx [BN*KK*DD]   = 16384
// 33792  : s      [BN*KK*DD]   = 16384   (zero block ends at 50176)
// 50176  : mu     [16384]
// 66560  : invsig [16384]
// 82944  : cc     [1024]
// 83968  : R      [BN*NN*KK]   = 2097152
// total 2181120 floats = 8.72 MB

__global__ void k_init(const float* __restrict__ mu0, float* __restrict__ mu,
                       float* __restrict__ invsig, float* __restrict__ cc) {
    int i = blockIdx.x * 256 + threadIdx.x;
    if (i < BN * KK * DD) { mu[i] = mu0[i]; invsig[i] = 1.0f; }
    if (i < BN * KK) cc[i] = -3.4657359028f;  // log(1/32)
}

// MODE 0: accumulate N, Sx, Sxx.  MODE 1: write R.
template <int MODE>
__global__ __launch_bounds__(256) void k_estep(
    const float* __restrict__ x, const float* __restrict__ mu,
    const float* __restrict__ invsig, const float* __restrict__ cc,
    float* __restrict__ accN, float* __restrict__ accSx,
    float* __restrict__ accSxx, float* __restrict__ Rout) {
    const int b = blockIdx.x >> 4;      // 32 b
    const int chunk = blockIdx.x & 15;  // 16 chunks of 128 n
    const int tid = threadIdx.x;
    const int wave = tid >> 6;
    const int lane = tid & 63;
    const int k = lane & 31;
    const int jj = lane >> 5;

    // per-lane cluster params in registers
    float mk[DD], ik[DD];
    {
        const float4* mp = (const float4*)(mu + (size_t)(b * KK + k) * DD);
        const float4* ip = (const float4*)(invsig + (size_t)(b * KK + k) * DD);
#pragma unroll
        for (int q = 0; q < 4; q++) {
            float4 m4 = mp[q], i4 = ip[q];
            mk[q*4+0]=m4.x; mk[q*4+1]=m4.y; mk[q*4+2]=m4.z; mk[q*4+3]=m4.w;
            ik[q*4+0]=i4.x; ik[q*4+1]=i4.y; ik[q*4+2]=i4.z; ik[q*4+3]=i4.w;
        }
    }
    const float ck = cc[b * KK + k];

    float aN = 0.f, aSx[DD], aSxx[DD];
#pragma unroll
    for (int d = 0; d < DD; d++) { aSx[d] = 0.f; aSxx[d] = 0.f; }

    for (int i = 0; i < 16; i++) {
        const int n = chunk * 128 + i * 8 + wave * 2 + jj;
        const float4* xp = (const float4*)(x + ((size_t)b * NN + n) * DD);
        float xv[DD];
#pragma unroll
        for (int q = 0; q < 4; q++) {
            float4 v = xp[q];
            xv[q*4+0]=v.x; xv[q*4+1]=v.y; xv[q*4+2]=v.z; xv[q*4+3]=v.w;
        }
        float qd = 0.f;
#pragma unroll
        for (int d = 0; d < DD; d++) {
            float z = (xv[d] - mk[d]) * ik[d];
            qd = fmaf(z, z, qd);
        }
        float logit = ck - 0.5f * qd;
        // softmax over k = 32 lanes of the half-wave
        float m = logit;
#pragma unroll
        for (int off = 1; off < 32; off <<= 1) m = fmaxf(m, __shfl_xor(m, off));
        float e = __expf(logit - m);
        float ssum = e;
#pragma unroll
        for (int off = 1; off < 32; off <<= 1) ssum += __shfl_xor(ssum, off);
        float g = e / ssum;

        if (MODE == 1) {
            Rout[((size_t)b * NN + n) * KK + k] = g;
        } else {
            aN += g;
#pragma unroll
            for (int d = 0; d < DD; d++) {
                aSx[d] = fmaf(g, xv[d], aSx[d]);
                aSxx[d] = fmaf(g * xv[d], xv[d], aSxx[d]);
            }
        }
    }

    if (MODE == 0) {
        __shared__ float red[4][KK * 33];
        aN += __shfl_xor(aN, 32);
#pragma unroll
        for (int d = 0; d < DD; d++) {
            aSx[d] += __shfl_xor(aSx[d], 32);
            aSxx[d] += __shfl_xor(aSxx[d], 32);
        }
        if (jj == 0) {
            red[wave][k * 33 + 0] = aN;
#pragma unroll
            for (int d = 0; d < DD; d++) {
                red[wave][k * 33 + 1 + d] = aSx[d];
                red[wave][k * 33 + 17 + d] = aSxx[d];
            }
        }
        __syncthreads();
        for (int idx = tid; idx < KK * 33; idx += 256) {
            float v = red[0][idx] + red[1][idx] + red[2][idx] + red[3][idx];
            int kk2 = idx / 33, j = idx % 33;
            float* dst;
            if (j == 0) dst = accN + b * KK + kk2;
            else if (j < 17) dst = accSx + (size_t)(b * KK + kk2) * DD + (j - 1);
            else dst = accSxx + (size_t)(b * KK + kk2) * DD + (j - 17);
            unsafeAtomicAdd(dst, v);
        }
    }
}

__global__ void k_finalize(float* __restrict__ accN, float* __restrict__ accSx,
                           float* __restrict__ accSxx, float* __restrict__ mu,
                           float* __restrict__ invsig, float* __restrict__ cc) {
    int i = blockIdx.x * 256 + threadIdx.x;  // (b,k)
    if (i >= BN * KK) return;
    float N = accN[i];
    accN[i] = 0.f;
    float invN = 1.0f / N;
    float sumlog = 0.f;
#pragma unroll
    for (int d = 0; d < DD; d++) {
        float m_ = accSx[(size_t)i * DD + d] * invN;
        float v = accSxx[(size_t)i * DD + d] * invN - m_ * m_;
        v = fmaxf(v, 1e-12f);
        mu[(size_t)i * DD + d] = m_;
        invsig[(size_t)i * DD + d] = rsqrtf(v);
        sumlog += 0.5f * logf(v);  // log(sigma)
        accSx[(size_t)i * DD + d] = 0.f;
        accSxx[(size_t)i * DD + d] = 0.f;
    }
    cc[i] = logf(N * (1.0f / NN)) - sumlog;
}

__device__ __forceinline__ float dot16(const float* w, float4 a, float4 b2,
                                       float4 c, float4 d2) {
    float s = 0.f;
    s = fmaf(w[0], a.x, s);  s = fmaf(w[1], a.y, s);
    s = fmaf(w[2], a.z, s);  s = fmaf(w[3], a.w, s);
    s = fmaf(w[4], b2.x, s); s = fmaf(w[5], b2.y, s);
    s = fmaf(w[6], b2.z, s); s = fmaf(w[7], b2.w, s);
    s = fmaf(w[8], c.x, s);  s = fmaf(w[9], c.y, s);
    s = fmaf(w[10], c.z, s); s = fmaf(w[11], c.w, s);
    s = fmaf(w[12], d2.x, s); s = fmaf(w[13], d2.y, s);
    s = fmaf(w[14], d2.z, s); s = fmaf(w[15], d2.w, s);
    return s;
}

// s[b,k,d] = sum_n R[b,n,k] * dot(W[n,k,d,:], x[b,n,:])
__global__ __launch_bounds__(256) void k_caps(
    const float* __restrict__ x, const float* __restrict__ W,
    const float* __restrict__ R, float* __restrict__ s) {
    __shared__ float xs[4][BN][DD];  // 8 KB
    __shared__ float rs[4][BN][KK];  // 16 KB
    const int t = threadIdx.x;
    const int n0 = blockIdx.x * 4;

    for (int q = t; q < 512; q += 256) {  // x: 4n*32b*16d = 512 float4
        int b = q >> 4, r = q & 15, j = r >> 2, e4 = r & 3;
        float4 v = *(const float4*)(x + (((size_t)b * NN + n0 + j) * DD + e4 * 4));
        *(float4*)&xs[j][b][e4 * 4] = v;
    }
    for (int q = t; q < 1024; q += 256) {  // R: 4n*32b*32k = 1024 float4
        int b = q >> 5, r = q & 31, j = r >> 3, k4 = r & 7;
        float4 v = *(const float4*)(R + (((size_t)b * NN + n0 + j) * KK + k4 * 4));
        *(float4*)&rs[j][b][k4 * 4] = v;
    }
    __syncthreads();

    const int k0 = t >> 4, k1 = k0 + 16, d = t & 15;
    float sacc0[BN], sacc1[BN];
#pragma unroll
    for (int b = 0; b < BN; b++) { sacc0[b] = 0.f; sacc1[b] = 0.f; }

    for (int j = 0; j < 4; j++) {
        float w0[16], w1[16];
        {
            const float4* wp0 = (const float4*)(W + (((size_t)(n0 + j) * KK + k0) * DD + d) * DD);
            const float4* wp1 = (const float4*)(W + (((size_t)(n0 + j) * KK + k1) * DD + d) * DD);
#pragma unroll
            for (int q = 0; q < 4; q++) {
                float4 a = wp0[q], b4 = wp1[q];
                w0[q*4+0]=a.x; w0[q*4+1]=a.y; w0[q*4+2]=a.z; w0[q*4+3]=a.w;
                w1[q*4+0]=b4.x; w1[q*4+1]=b4.y; w1[q*4+2]=b4.z; w1[q*4+3]=b4.w;
            }
        }
#pragma unroll
        for (int b = 0; b < BN; b++) {
            const float4* xv = (const float4*)&xs[j][b][0];
            float4 a = xv[0], b2 = xv[1], c = xv[2], d2 = xv[3];
            float caps0 = dot16(w0, a, b2, c, d2);
            float caps1 = dot16(w1, a, b2, c, d2);
            sacc0[b] = fmaf(rs[j][b][k0], caps0, sacc0[b]);
            sacc1[b] = fmaf(rs[j][b][k1], caps1, sacc1[b]);
        }
    }
#pragma unroll
    for (int b = 0; b < BN; b++) {
        unsafeAtomicAdd(s + ((size_t)b * KK + k0) * DD + d, sacc0[b]);
        unsafeAtomicAdd(s + ((size_t)b * KK + k1) * DD + d, sacc1[b]);
    }
}

__global__ void k_squash(const float* __restrict__ s, float* __restrict__ out) {
    int i = blockIdx.x * 256 + threadIdx.x;  // (b,k)
    if (i >= BN * KK) return;
    const float4* sp = (const float4*)(s + (size_t)i * DD);
    float4 v0 = sp[0], v1 = sp[1], v2 = sp[2], v3 = sp[3];
    float ss = 1e-7f;
    ss += v0.x*v0.x + v0.y*v0.y + v0.z*v0.z + v0.w*v0.w;
    ss += v1.x*v1.x + v1.y*v1.y + v1.z*v1.z + v1.w*v1.w;
    ss += v2.x*v2.x + v2.y*v2.y + v2.z*v2.z + v2.w*v2.w;
    ss += v3.x*v3.x + v3.y*v3.y + v3.z*v3.z + v3.w*v3.w;
    float sc = sqrtf(ss) / (1.0f + ss);
    float4* op = (float4*)(out + (size_t)i * DD);
    v0.x*=sc; v0.y*=sc; v0.z*=sc; v0.w*=sc;
    v1.x*=sc; v1.y*=sc; v1.z*=sc; v1.w*=sc;
    v2.x*=sc; v2.y*=sc; v2.z*=sc; v2.w*=sc;
    v3.x*=sc; v3.y*=sc; v3.z*=sc; v3.w*=sc;
    op[0]=v0; op[1]=v1; op[2]=v2; op[3]=v3;
}

extern "C" void kernel_launch(void* const* d_in, const int* in_sizes, int n_in,
                              void* d_out, int out_size, void* d_ws, size_t ws_size,
                              hipStream_t stream) {
    const float* x   = (const float*)d_in[0];
    const float* W   = (const float*)d_in[1];
    const float* mu0 = (const float*)d_in[2];
    float* ws      = (float*)d_ws;
    float* accN    = ws;
    float* accSx   = ws + 1024;
    float* accSxx  = ws + 17408;
    float* s       = ws + 33792;
    float* mu      = ws + 50176;
    float* invsig  = ws + 66560;
    float* cc      = ws + 82944;
    float* R       = ws + 83968;

    hipMemsetAsync(ws, 0, (size_t)50176 * sizeof(float), stream);
    k_init<<<64, 256, 0, stream>>>(mu0, mu, invsig, cc);

    // iteration 1
    k_estep<0><<<512, 256, 0, stream>>>(x, mu, invsig, cc, accN, accSx, accSxx, nullptr);
    k_finalize<<<4, 256, 0, stream>>>(accN, accSx, accSxx, mu, invsig, cc);
    // iteration 2
    k_estep<0><<<512, 256, 0, stream>>>(x, mu, invsig, cc, accN, accSx, accSxx, nullptr);
    k_finalize<<<4, 256, 0, stream>>>(accN, accSx, accSxx, mu, invsig, cc);
    // iteration 3: only R is needed downstream
    k_estep<1><<<512, 256, 0, stream>>>(x, mu, invsig, cc, nullptr, nullptr, nullptr, R);

    k_caps<<<512, 256, 0, stream>>>(x, W, R, s);
    k_squash<<<4, 256, 0, stream>>>(s, (float*)d_out);
}